// Round 11
// baseline (768.367 us; speedup 1.0000x reference)
//
#include <hip/hip_runtime.h>

typedef float floatx4 __attribute__((ext_vector_type(4)));
typedef short shortx8 __attribute__((ext_vector_type(8)));

#define T_SEQ 2048
#define NQH   32
#define NKVH  8
#define HD    64
#define DM    2048
#define NTOT  3072

#if __has_builtin(__builtin_amdgcn_exp2f)
#define EXP2F(x) __builtin_amdgcn_exp2f(x)
#else
#define EXP2F(x) exp2f(x)
#endif

__device__ __forceinline__ unsigned short f2bf(float f) {
    unsigned int u = __builtin_bit_cast(unsigned int, f);
    u += 0x7FFFu + ((u >> 16) & 1u);          // RNE
    return (unsigned short)(u >> 16);
}
__device__ __forceinline__ unsigned int pk2bf(float a, float b) {
    return (unsigned int)f2bf(a) | ((unsigned int)f2bf(b) << 16);
}

// v_cvt_pk_bf16_f32: dst = {lo16=bf16(lo), hi16=bf16(hi)}, RNE, 1 instr
__device__ __forceinline__ unsigned int cvtpk_bf16(float lo, float hi) {
    unsigned int r;
    asm("v_cvt_pk_bf16_f32 %0, %1, %2" : "=v"(r) : "v"(lo), "v"(hi));
    return r;
}

// async global->LDS, 16B per lane; LDS dest = wave-uniform base + lane*16
__device__ __forceinline__ void dma16(const unsigned short* g, unsigned short* l) {
    __builtin_amdgcn_global_load_lds(
        (const __attribute__((address_space(1))) unsigned int*)g,
        (__attribute__((address_space(3))) unsigned int*)l,
        16, 0, 0);
}

// ---------------------------------------------------------------------------
// W transpose-convert only (R11: the x fp32->bf16 pass moved INTO qkv_gemm's
// A-staging, deleting 50 MB of stream traffic + 4096 blocks from this kernel).
// R5's XOR-granule-swizzled LDS transpose, verbatim: write k-pairs as b32
// scatter (granule (k>>3)^((n>>3)&7): 32 banks, 2 lanes/bank = free), read
// rows as full-rate b128.
// ---------------------------------------------------------------------------
__global__ __launch_bounds__(256) void cvt_w(
    const float* __restrict__ Wq, const float* __restrict__ Wk,
    const float* __restrict__ Wv, unsigned short* __restrict__ wt)
{
    __shared__ __align__(16) unsigned short Ts[64 * 64];   // logical [n][k], swizzled
    const int id2 = blockIdx.x;               // 0..1535
    const int t = threadIdx.x;
    const int k0 = (id2 & 31) * 64, n0g = (id2 >> 5) * 64;
    const float* W; int ldW, col0;
    if (n0g < 2048)      { W = Wq; ldW = 2048; col0 = n0g; }
    else if (n0g < 2560) { W = Wk; ldW = 512;  col0 = n0g - 2048; }
    else                 { W = Wv; ldW = 512;  col0 = n0g - 2560; }
    {
        // thread: k rows {2R, 2R+1}, n cols C..C+7
        const int R = t >> 3, C = (t & 7) * 8;
        const float* src0 = W + (size_t)(k0 + 2 * R) * ldW + col0 + C;
        const float* src1 = src0 + ldW;
        float4 a0 = *(const float4*)(src0);
        float4 a1 = *(const float4*)(src0 + 4);
        float4 b0 = *(const float4*)(src1);
        float4 b1 = *(const float4*)(src1 + 4);
        float lo[8] = {a0.x, a0.y, a0.z, a0.w, a1.x, a1.y, a1.z, a1.w};
        float hi[8] = {b0.x, b0.y, b0.z, b0.w, b1.x, b1.y, b1.z, b1.w};
        const int g = R >> 2;                 // granule of k=2R
        const int ko = (2 * R) & 7;           // short offset within granule (even)
        #pragma unroll
        for (int i = 0; i < 8; i++) {
            const int n = C + i;
            const int gp = g ^ ((n >> 3) & 7);
            *(unsigned int*)&Ts[n * 64 + gp * 8 + ko] = pk2bf(lo[i], hi[i]);
        }
    }
    __syncthreads();
    {
        const int n = t >> 2, kc = (t & 3) * 16;
        const int f = (n >> 3) & 7;
        const int g0 = kc >> 3;
        uint4 o0 = *(const uint4*)&Ts[n * 64 + ((g0)     ^ f) * 8];
        uint4 o1 = *(const uint4*)&Ts[n * 64 + ((g0 + 1) ^ f) * 8];
        unsigned short* d = wt + (size_t)(n0g + n) * DM + k0 + kc;
        *(uint4*)d = o0; *(uint4*)(d + 8) = o1;
    }
}

// ---------------------------------------------------------------------------
// Fused QKV GEMM, m97 single-buffer structure (proven ~61us). R11: A-operand
// read DIRECTLY from x (fp32) with in-register bf16 conversion — the old
// cvt x-pass (50 MB stream) is deleted. T14 async-STAGE split: the 8 float4
// loads of next tile's A rows issue at barrier1 and fly across the MFMA
// phase; after barrier2 (all LDS readers done) they convert via pk2bf and
// ds_write_b128 to the BYTE-IDENTICAL addresses dma16 produced
// (base + lane*16, same cgw swizzle) — fragment readers untouched.
// B-side keeps dma16 from wt. Single-buffer WAR semantics unchanged.
// ---------------------------------------------------------------------------
__global__ __launch_bounds__(256, 4) void qkv_gemm(
    const float* __restrict__ x,             // [4096][2048] fp32
    const unsigned short* __restrict__ wt,   // [3072][2048] bf16
    unsigned short* __restrict__ Qws, unsigned short* __restrict__ Kws,
    unsigned short* __restrict__ Vws)
{
    __shared__ __align__(16) unsigned short At[128 * 64];
    __shared__ __align__(16) unsigned short Bt[128 * 64];

    const int tid = threadIdx.x;
    const int wave = tid >> 6, lane = tid & 63;
    const int l16 = lane & 15, qd = lane >> 4;

    const int id  = blockIdx.y * 24 + blockIdx.x;       // 0..767
    const int xcd = id & 7, j = id >> 3;                // j 0..95
    const int m0 = (xcd * 4 + (j & 3)) * 128;           // 32 m-tiles
    const int n0 = (j >> 2) * 128;                      // 24 n-tiles

    const int mh = (wave >> 1) * 64, nh = (wave & 1) * 64;

    const int lrow = lane >> 3;
    const int cgw  = (lane & 7) ^ lrow;            // staging global col-group swizzle
    const int cg0  = (qd ^ (l16 & 7)) * 8;         // frag col offset, ks=0
    const int cg1  = ((4 | qd) ^ (l16 & 7)) * 8;   // ks=1

    floatx4 acc[4][4];
    #pragma unroll
    for (int mi = 0; mi < 4; mi++)
        #pragma unroll
        for (int ni = 0; ni < 4; ni++)
            acc[mi][ni] = (floatx4){0.f, 0.f, 0.f, 0.f};

    size_t gA[4], gB[4];
    int lofs[4];
    #pragma unroll
    for (int jj = 0; jj < 4; jj++) {
        const int rb = wave * 32 + jj * 8;
        gA[jj] = (size_t)(m0 + rb + lrow) * DM + cgw * 8;   // f32 elements
        gB[jj] = (size_t)(n0 + rb + lrow) * DM + cgw * 8;   // bf16 elements
        lofs[jj] = rb * 64;
    }

    float4 fa[4][2];    // in-flight A rows (f32), static-indexed (rule #20)

#define LOAD_AX(k0off) { _Pragma("unroll") for (int jj = 0; jj < 4; jj++) { \
    const float* s = x + gA[jj] + (k0off); \
    fa[jj][0] = *(const float4*)s; \
    fa[jj][1] = *(const float4*)(s + 4); } }

#define WRITE_A() { _Pragma("unroll") for (int jj = 0; jj < 4; jj++) { \
    uint4 o; \
    o.x = pk2bf(fa[jj][0].x, fa[jj][0].y); \
    o.y = pk2bf(fa[jj][0].z, fa[jj][0].w); \
    o.z = pk2bf(fa[jj][1].x, fa[jj][1].y); \
    o.w = pk2bf(fa[jj][1].z, fa[jj][1].w); \
    *(uint4*)&At[lofs[jj] + lane * 8] = o; } }

    // prologue: stage tile 0 (A converted in-register, B via async DMA)
    LOAD_AX(0);
    WRITE_A();
    #pragma unroll
    for (int jj = 0; jj < 4; jj++)
        dma16(wt + gB[jj], &Bt[lofs[jj]]);

    for (int k0 = 0; k0 < DM; k0 += 64) {
        const bool pf = (k0 + 64 < DM);
        __syncthreads();          // tile k0 landed (B vmcnt-drained, A ds_writes lgkm-drained)
        if (pf) LOAD_AX(k0 + 64); // issue next A loads; latency hides under MFMA phase
        #pragma unroll
        for (int ks = 0; ks < 2; ks++) {
            const int cg = ks ? cg1 : cg0;
            shortx8 af[4], bfr[4];
            #pragma unroll
            for (int i = 0; i < 4; i++) {
                af[i]  = *(const shortx8*)&At[(mh + i * 16 + l16) * 64 + cg];
                bfr[i] = *(const shortx8*)&Bt[(nh + i * 16 + l16) * 64 + cg];
            }
            #pragma unroll
            for (int mi = 0; mi < 4; mi++)
                #pragma unroll
                for (int ni = 0; ni < 4; ni++)
                    acc[mi][ni] = __builtin_amdgcn_mfma_f32_16x16x32_bf16(
                        af[mi], bfr[ni], acc[mi][ni], 0, 0, 0);
        }
        __syncthreads();          // all waves done reading LDS
        if (pf) {
            WRITE_A();            // convert + write next A (loads have landed)
            #pragma unroll
            for (int jj = 0; jj < 4; jj++)
                dma16(wt + gB[jj] + k0 + 64, &Bt[lofs[jj]]);
        }
    }
#undef LOAD_AX
#undef WRITE_A

    int ncol, H; unsigned short* dst; float sc; bool vtrans;
    if (n0 < 2048)      { ncol = n0;        dst = Qws; H = NQH;  sc = 0.125f * 1.44269504f; vtrans = false; }
    else if (n0 < 2560) { ncol = n0 - 2048; dst = Kws; H = NKVH; sc = 1.0f; vtrans = false; }
    else                { ncol = n0 - 2560; dst = Vws; H = NKVH; sc = 1.0f; vtrans = true;  }

    #pragma unroll
    for (int mi = 0; mi < 4; mi++)
        #pragma unroll
        for (int ni = 0; ni < 4; ni++)
            #pragma unroll
            for (int r = 0; r < 4; r++) {
                int m  = m0 + mh + mi * 16 + qd * 4 + r;
                int nc = ncol + nh + ni * 16 + l16;
                int b  = m >> 11, t = m & (T_SEQ - 1);
                int hh = nc >> 6, d = nc & 63;
                float v = acc[mi][ni][r] * sc;
                size_t idx = vtrans
                    ? ((((size_t)b * H + hh) * HD + d) << 11) + t
                    : ((((size_t)b * H + hh) * T_SEQ + t) << 6) + d;
                dst[idx] = f2bf(v);
            }
}

// ---------------------------------------------------------------------------
// Causal GQA flash attention, transposed form: S^T = K Q^T, O^T = V^T P^T.
// Reverted to the PROVEN R2 body (60.0us measured): serial per-kp chunk body,
// 2 buffers, __syncthreads full-drain per chunk. The kp-pipelined variant
// (R10) measured slower (63) and the counted-vmcnt staging (R7/R8) corrupts.
// 8 waves x 512 threads; row-sum fused into an all-ones MFMA; P pack via
// v_cvt_pk_bf16_f32; diag-chunk wave-half skip; setprio(1) around PV.
// ---------------------------------------------------------------------------
__global__ __launch_bounds__(512, 4) void attn_fwd(
    const unsigned short* __restrict__ Qws,
    const unsigned short* __restrict__ Kws,
    const unsigned short* __restrict__ Vtws,
    float* __restrict__ out)
{
    __shared__ __align__(16) unsigned short Ks[2][64 * 64];
    __shared__ __align__(16) unsigned short Vt[2][64 * 64];
    __shared__ __align__(16) unsigned short Ps[8][32][40];   // per-wave [q in 32][key in 32-window]

    const int tid = threadIdx.x;
    const int wave = tid >> 6, lane = tid & 63;
    const int whead = wave & 3, wrow = wave >> 2;
    const int l16 = lane & 15, qd = lane >> 4;
    const int b = blockIdx.z;
    const int qt = b ? blockIdx.x : (31 - blockIdx.x);   // CU-pair makespan balance
    const int kh = blockIdx.y;
    const int h = kh * 4 + whead;
    const int q0 = qt * 64;
    const int mh = wrow * 32;

    const size_t qbase  = (((size_t)b * NQH + h) * T_SEQ + q0) * HD;
    const size_t kbase  = ((size_t)b * NKVH + kh) * (size_t)T_SEQ * HD;
    const size_t vtbase = ((size_t)b * NKVH + kh) * (size_t)HD * T_SEQ;

    // Q fragments (B operand), 32 rows per wave
    shortx8 qfr[2][2];
    #pragma unroll
    for (int mqt = 0; mqt < 2; mqt++)
        #pragma unroll
        for (int ks = 0; ks < 2; ks++)
            qfr[mqt][ks] = *(const shortx8*)(Qws + qbase +
                (size_t)(mh + mqt * 16 + l16) * HD + ks * 32 + qd * 8);

    const shortx8 ones = {0x3F80, 0x3F80, 0x3F80, 0x3F80,
                          0x3F80, 0x3F80, 0x3F80, 0x3F80};  // bf16 1.0

    floatx4 oaccT[2][4];      // [mqt][dt]: O^T tile, col q = l16, rows d = qd*4+r
    #pragma unroll
    for (int mqt = 0; mqt < 2; mqt++)
        #pragma unroll
        for (int dt = 0; dt < 4; dt++)
            oaccT[mqt][dt] = (floatx4){0.f, 0.f, 0.f, 0.f};
    floatx4 psum[2];          // ones^T P^T: every element = full row-sum for q=l16
    psum[0] = (floatx4){0.f, 0.f, 0.f, 0.f};
    psum[1] = (floatx4){0.f, 0.f, 0.f, 0.f};

    const int lrow = lane >> 3;
    const int cgw  = (lane & 7) ^ lrow;
    const int xr   = l16 & 7;
    const int rb   = wave * 8;     // 8 waves x 8 rows = 64 rows per buffer

    // prologue: stage chunk 0 into buffer 0
    dma16(Kws  + kbase  + (size_t)(rb + lrow) * HD + cgw * 8, &Ks[0][rb * 64]);
    dma16(Vtws + vtbase + (size_t)(rb + lrow) * T_SEQ + cgw * 8, &Vt[0][rb * 64]);

    for (int c = 0; c <= qt; c++) {
        const int cur = c & 1;
        __syncthreads();          // chunk c landed; buffer cur^1 free
        if (c < qt) {
            const int j0n = (c + 1) * 64;
            dma16(Kws  + kbase  + (size_t)(j0n + rb + lrow) * HD + cgw * 8,
                  &Ks[cur ^ 1][rb * 64]);
            dma16(Vtws + vtbase + (size_t)(rb + lrow) * T_SEQ + j0n + cgw * 8,
                  &Vt[cur ^ 1][rb * 64]);
        }

        const bool diag = (c == qt);

        #pragma unroll
        for (int kp = 0; kp < 2; kp++) {
            // diag chunk, row-half 0: keys 32..63 all > q rows 0..31 -> skip
            if (!(diag && wrow == 0 && kp == 1)) {
                // K fragments (A operand) for this 32-key window
                shortx8 kf[2][2];
                #pragma unroll
                for (int ktl = 0; ktl < 2; ktl++) {
                    const int krow = ((kp * 2 + ktl) * 16 + l16) * 64;
                    kf[ktl][0] = *(const shortx8*)&Ks[cur][krow + ((qd ^ xr) * 8)];
                    kf[ktl][1] = *(const shortx8*)&Ks[cur][krow + (((4 | qd) ^ xr) * 8)];
                }

                const bool msk = diag && (wrow == kp);   // diag window straddles row-half

                // ---- S^T = K Q^T, P = 2^S (bf16 RNE via cvt_pk), spill b64 ----
                #pragma unroll
                for (int ktl = 0; ktl < 2; ktl++) {
                    #pragma unroll
                    for (int mqt = 0; mqt < 2; mqt++) {
                        floatx4 s = (floatx4){0.f, 0.f, 0.f, 0.f};
                        s = __builtin_amdgcn_mfma_f32_16x16x32_bf16(kf[ktl][0], qfr[mqt][0], s, 0, 0, 0);
                        s = __builtin_amdgcn_mfma_f32_16x16x32_bf16(kf[ktl][1], qfr[mqt][1], s, 0, 0, 0);
                        float pe[4];
                        #pragma unroll
                        for (int r = 0; r < 4; r++) pe[r] = EXP2F(s[r]);
                        if (msk) {
                            const int qrel  = mh + mqt * 16 + l16;
                            const int jbase = kp * 32 + ktl * 16 + qd * 4;
                            #pragma unroll
                            for (int r = 0; r < 4; r++)
                                if (jbase + r > qrel) pe[r] = 0.f;
                        }
                        uint2 dw;
                        dw.x = cvtpk_bf16(pe[0], pe[1]);
                        dw.y = cvtpk_bf16(pe[2], pe[3]);
                        *(uint2*)&Ps[wave][mqt * 16 + l16][ktl * 16 + qd * 4] = dw;
                    }
                }

                // ---- P^T fragments (B operand; same-wave LDS round trip) ----
                shortx8 pfr[2];
                #pragma unroll
                for (int mqt = 0; mqt < 2; mqt++)
                    pfr[mqt] = *(const shortx8*)&Ps[wave][mqt * 16 + l16][qd * 8];

                // ---- row-sum fused as MFMA: psum += 1 * P^T ----
                #pragma unroll
                for (int mqt = 0; mqt < 2; mqt++)
                    psum[mqt] = __builtin_amdgcn_mfma_f32_16x16x32_bf16(
                        ones, pfr[mqt], psum[mqt], 0, 0, 0);

                // ---- O^T += V^T P^T ----
                __builtin_amdgcn_s_setprio(1);
                #pragma unroll
                for (int dt = 0; dt < 4; dt++) {
                    const shortx8 vf = *(const shortx8*)
                        &Vt[cur][(dt * 16 + l16) * 64 + (((kp * 4 + qd) ^ xr) * 8)];
                    #pragma unroll
                    for (int mqt = 0; mqt < 2; mqt++)
                        oaccT[mqt][dt] = __builtin_amdgcn_mfma_f32_16x16x32_bf16(
                            vf, pfr[mqt], oaccT[mqt][dt], 0, 0, 0);
                }
                __builtin_amdgcn_s_setprio(0);
            }
        }
    }

    // psum rows are identical (A = ones) -> denominator lane-local, no shuffles
    float inv[2];
    inv[0] = 1.f / psum[0][0];
    inv[1] = 1.f / psum[1][0];

    // ---- epilogue: O^T C-layout (col q = l16, rows d = qd*4+r) -> float4 ----
    #pragma unroll
    for (int mqt = 0; mqt < 2; mqt++) {
        const int t = q0 + mh + mqt * 16 + l16;
        float* orow = out + ((size_t)b * T_SEQ + t) * (NQH * HD) + h * HD + qd * 4;
        #pragma unroll
        for (int dt = 0; dt < 4; dt++) {
            float4 o;
            o.x = oaccT[mqt][dt][0] * inv[mqt];
            o.y = oaccT[mqt][dt][1] * inv[mqt];
            o.z = oaccT[mqt][dt][2] * inv[mqt];
            o.w = oaccT[mqt][dt][3] * inv[mqt];
            *(float4*)(orow + dt * 16) = o;
        }
    }
}

extern "C" void kernel_launch(void* const* d_in, const int* in_sizes, int n_in,
                              void* d_out, int out_size, void* d_ws, size_t ws_size,
                              hipStream_t stream) {
    const float* x  = (const float*)d_in[0];
    const float* Wq = (const float*)d_in[1];
    const float* Wk = (const float*)d_in[2];
    const float* Wv = (const float*)d_in[3];
    float* out = (float*)d_out;

    unsigned short* wt  = (unsigned short*)d_ws;                  // 12.6 MB
    unsigned short* Qws = wt  + (size_t)NTOT * DM;                // 16.8 MB
    unsigned short* Kws = Qws + (size_t)2 * NQH * T_SEQ * HD;     // 4.2 MB
    unsigned short* Vws = Kws + (size_t)2 * NKVH * T_SEQ * HD;    // 4.2 MB

    cvt_w   <<<1536, 256, 0, stream>>>(Wq, Wk, Wv, wt);
    qkv_gemm<<<dim3(24, 32), 256, 0, stream>>>(x, wt, Qws, Kws, Vws);
    attn_fwd<<<dim3(32, NKVH, 2), 512, 0, stream>>>(Qws, Kws, Vws, out);
}

// Round 12
// 277.832 us; speedup vs baseline: 2.7656x; 2.7656x over previous
//
#include <hip/hip_runtime.h>

typedef float floatx4 __attribute__((ext_vector_type(4)));
typedef short shortx8 __attribute__((ext_vector_type(8)));

#define T_SEQ 2048
#define NQH   32
#define NKVH  8
#define HD    64
#define DM    2048
#define NTOT  3072

#if __has_builtin(__builtin_amdgcn_exp2f)
#define EXP2F(x) __builtin_amdgcn_exp2f(x)
#else
#define EXP2F(x) exp2f(x)
#endif

__device__ __forceinline__ unsigned short f2bf(float f) {
    unsigned int u = __builtin_bit_cast(unsigned int, f);
    u += 0x7FFFu + ((u >> 16) & 1u);          // RNE
    return (unsigned short)(u >> 16);
}
__device__ __forceinline__ unsigned int pk2bf(float a, float b) {
    return (unsigned int)f2bf(a) | ((unsigned int)f2bf(b) << 16);
}

// v_cvt_pk_bf16_f32: dst = {lo16=bf16(lo), hi16=bf16(hi)}, RNE, 1 instr
__device__ __forceinline__ unsigned int cvtpk_bf16(float lo, float hi) {
    unsigned int r;
    asm("v_cvt_pk_bf16_f32 %0, %1, %2" : "=v"(r) : "v"(lo), "v"(hi));
    return r;
}

// async global->LDS, 16B per lane; LDS dest = wave-uniform base + lane*16
__device__ __forceinline__ void dma16(const unsigned short* g, unsigned short* l) {
    __builtin_amdgcn_global_load_lds(
        (const __attribute__((address_space(1))) unsigned int*)g,
        (__attribute__((address_space(3))) unsigned int*)l,
        16, 0, 0);
}

// ---------------------------------------------------------------------------
// W transpose-convert only. R5's XOR-granule-swizzled LDS transpose, verbatim.
// ---------------------------------------------------------------------------
__global__ __launch_bounds__(256) void cvt_w(
    const float* __restrict__ Wq, const float* __restrict__ Wk,
    const float* __restrict__ Wv, unsigned short* __restrict__ wt)
{
    __shared__ __align__(16) unsigned short Ts[64 * 64];   // logical [n][k], swizzled
    const int id2 = blockIdx.x;               // 0..1535
    const int t = threadIdx.x;
    const int k0 = (id2 & 31) * 64, n0g = (id2 >> 5) * 64;
    const float* W; int ldW, col0;
    if (n0g < 2048)      { W = Wq; ldW = 2048; col0 = n0g; }
    else if (n0g < 2560) { W = Wk; ldW = 512;  col0 = n0g - 2048; }
    else                 { W = Wv; ldW = 512;  col0 = n0g - 2560; }
    {
        // thread: k rows {2R, 2R+1}, n cols C..C+7
        const int R = t >> 3, C = (t & 7) * 8;
        const float* src0 = W + (size_t)(k0 + 2 * R) * ldW + col0 + C;
        const float* src1 = src0 + ldW;
        float4 a0 = *(const float4*)(src0);
        float4 a1 = *(const float4*)(src0 + 4);
        float4 b0 = *(const float4*)(src1);
        float4 b1 = *(const float4*)(src1 + 4);
        float lo[8] = {a0.x, a0.y, a0.z, a0.w, a1.x, a1.y, a1.z, a1.w};
        float hi[8] = {b0.x, b0.y, b0.z, b0.w, b1.x, b1.y, b1.z, b1.w};
        const int g = R >> 2;                 // granule of k=2R
        const int ko = (2 * R) & 7;           // short offset within granule (even)
        #pragma unroll
        for (int i = 0; i < 8; i++) {
            const int n = C + i;
            const int gp = g ^ ((n >> 3) & 7);
            *(unsigned int*)&Ts[n * 64 + gp * 8 + ko] = pk2bf(lo[i], hi[i]);
        }
    }
    __syncthreads();
    {
        const int n = t >> 2, kc = (t & 3) * 16;
        const int f = (n >> 3) & 7;
        const int g0 = kc >> 3;
        uint4 o0 = *(const uint4*)&Ts[n * 64 + ((g0)     ^ f) * 8];
        uint4 o1 = *(const uint4*)&Ts[n * 64 + ((g0 + 1) ^ f) * 8];
        unsigned short* d = wt + (size_t)(n0g + n) * DM + k0 + kc;
        *(uint4*)d = o0; *(uint4*)(d + 8) = o1;
    }
}

// ---------------------------------------------------------------------------
// Fused QKV GEMM, m97 single-buffer structure, A converted from x (fp32)
// in-flight. R12 fix: R11's 768us regression was SCRATCH SPILL — holding
// fa[4][2] (32 VGPR) across the MFMA phase pushed the live set to ~140 VGPR
// while __launch_bounds__(256,4) capped the allocator at 128 -> 780MB of
// spill traffic (WRITE_SIZE 1.9GB). Fix: (256,3) -> 170-VGPR cap, no spill;
// 3 blocks/CU x 256 CU = 768 = grid, still exactly one dispatch round.
// ---------------------------------------------------------------------------
__global__ __launch_bounds__(256, 3) void qkv_gemm(
    const float* __restrict__ x,             // [4096][2048] fp32
    const unsigned short* __restrict__ wt,   // [3072][2048] bf16
    unsigned short* __restrict__ Qws, unsigned short* __restrict__ Kws,
    unsigned short* __restrict__ Vws)
{
    __shared__ __align__(16) unsigned short At[128 * 64];
    __shared__ __align__(16) unsigned short Bt[128 * 64];

    const int tid = threadIdx.x;
    const int wave = tid >> 6, lane = tid & 63;
    const int l16 = lane & 15, qd = lane >> 4;

    const int id  = blockIdx.y * 24 + blockIdx.x;       // 0..767
    const int xcd = id & 7, j = id >> 3;                // j 0..95
    const int m0 = (xcd * 4 + (j & 3)) * 128;           // 32 m-tiles
    const int n0 = (j >> 2) * 128;                      // 24 n-tiles

    const int mh = (wave >> 1) * 64, nh = (wave & 1) * 64;

    const int lrow = lane >> 3;
    const int cgw  = (lane & 7) ^ lrow;            // staging global col-group swizzle
    const int cg0  = (qd ^ (l16 & 7)) * 8;         // frag col offset, ks=0
    const int cg1  = ((4 | qd) ^ (l16 & 7)) * 8;   // ks=1

    floatx4 acc[4][4];
    #pragma unroll
    for (int mi = 0; mi < 4; mi++)
        #pragma unroll
        for (int ni = 0; ni < 4; ni++)
            acc[mi][ni] = (floatx4){0.f, 0.f, 0.f, 0.f};

    size_t gA[4], gB[4];
    int lofs[4];
    #pragma unroll
    for (int jj = 0; jj < 4; jj++) {
        const int rb = wave * 32 + jj * 8;
        gA[jj] = (size_t)(m0 + rb + lrow) * DM + cgw * 8;   // f32 elements
        gB[jj] = (size_t)(n0 + rb + lrow) * DM + cgw * 8;   // bf16 elements
        lofs[jj] = rb * 64;
    }

    float4 fa[4][2];    // in-flight A rows (f32), static-indexed (rule #20)

#define LOAD_AX(k0off) { _Pragma("unroll") for (int jj = 0; jj < 4; jj++) { \
    const float* s = x + gA[jj] + (k0off); \
    fa[jj][0] = *(const float4*)s; \
    fa[jj][1] = *(const float4*)(s + 4); } }

#define WRITE_A() { _Pragma("unroll") for (int jj = 0; jj < 4; jj++) { \
    uint4 o; \
    o.x = pk2bf(fa[jj][0].x, fa[jj][0].y); \
    o.y = pk2bf(fa[jj][0].z, fa[jj][0].w); \
    o.z = pk2bf(fa[jj][1].x, fa[jj][1].y); \
    o.w = pk2bf(fa[jj][1].z, fa[jj][1].w); \
    *(uint4*)&At[lofs[jj] + lane * 8] = o; } }

    // prologue: stage tile 0 (A converted in-register, B via async DMA)
    LOAD_AX(0);
    WRITE_A();
    #pragma unroll
    for (int jj = 0; jj < 4; jj++)
        dma16(wt + gB[jj], &Bt[lofs[jj]]);

    for (int k0 = 0; k0 < DM; k0 += 64) {
        const bool pf = (k0 + 64 < DM);
        __syncthreads();          // tile k0 landed (B vmcnt-drained, A ds_writes lgkm-drained)
        if (pf) LOAD_AX(k0 + 64); // issue next A loads; latency hides under MFMA phase
        #pragma unroll
        for (int ks = 0; ks < 2; ks++) {
            const int cg = ks ? cg1 : cg0;
            shortx8 af[4], bfr[4];
            #pragma unroll
            for (int i = 0; i < 4; i++) {
                af[i]  = *(const shortx8*)&At[(mh + i * 16 + l16) * 64 + cg];
                bfr[i] = *(const shortx8*)&Bt[(nh + i * 16 + l16) * 64 + cg];
            }
            #pragma unroll
            for (int mi = 0; mi < 4; mi++)
                #pragma unroll
                for (int ni = 0; ni < 4; ni++)
                    acc[mi][ni] = __builtin_amdgcn_mfma_f32_16x16x32_bf16(
                        af[mi], bfr[ni], acc[mi][ni], 0, 0, 0);
        }
        __syncthreads();          // all waves done reading LDS
        if (pf) {
            WRITE_A();            // convert + write next A (loads have landed)
            #pragma unroll
            for (int jj = 0; jj < 4; jj++)
                dma16(wt + gB[jj] + k0 + 64, &Bt[lofs[jj]]);
        }
    }
#undef LOAD_AX
#undef WRITE_A

    int ncol, H; unsigned short* dst; float sc; bool vtrans;
    if (n0 < 2048)      { ncol = n0;        dst = Qws; H = NQH;  sc = 0.125f * 1.44269504f; vtrans = false; }
    else if (n0 < 2560) { ncol = n0 - 2048; dst = Kws; H = NKVH; sc = 1.0f; vtrans = false; }
    else                { ncol = n0 - 2560; dst = Vws; H = NKVH; sc = 1.0f; vtrans = true;  }

    #pragma unroll
    for (int mi = 0; mi < 4; mi++)
        #pragma unroll
        for (int ni = 0; ni < 4; ni++)
            #pragma unroll
            for (int r = 0; r < 4; r++) {
                int m  = m0 + mh + mi * 16 + qd * 4 + r;
                int nc = ncol + nh + ni * 16 + l16;
                int b  = m >> 11, t = m & (T_SEQ - 1);
                int hh = nc >> 6, d = nc & 63;
                float v = acc[mi][ni][r] * sc;
                size_t idx = vtrans
                    ? ((((size_t)b * H + hh) * HD + d) << 11) + t
                    : ((((size_t)b * H + hh) * T_SEQ + t) << 6) + d;
                dst[idx] = f2bf(v);
            }
}

// ---------------------------------------------------------------------------
// Causal GQA flash attention, transposed form: S^T = K Q^T, O^T = V^T P^T.
// PROVEN R2 body (60.0us measured): serial per-kp chunk body, 2 buffers,
// __syncthreads full-drain per chunk. 8 waves x 512 threads; row-sum fused
// into an all-ones MFMA; P pack via v_cvt_pk_bf16_f32; diag-chunk wave-half
// skip; setprio(1) around PV.
// ---------------------------------------------------------------------------
__global__ __launch_bounds__(512, 4) void attn_fwd(
    const unsigned short* __restrict__ Qws,
    const unsigned short* __restrict__ Kws,
    const unsigned short* __restrict__ Vtws,
    float* __restrict__ out)
{
    __shared__ __align__(16) unsigned short Ks[2][64 * 64];
    __shared__ __align__(16) unsigned short Vt[2][64 * 64];
    __shared__ __align__(16) unsigned short Ps[8][32][40];   // per-wave [q in 32][key in 32-window]

    const int tid = threadIdx.x;
    const int wave = tid >> 6, lane = tid & 63;
    const int whead = wave & 3, wrow = wave >> 2;
    const int l16 = lane & 15, qd = lane >> 4;
    const int b = blockIdx.z;
    const int qt = b ? blockIdx.x : (31 - blockIdx.x);   // CU-pair makespan balance
    const int kh = blockIdx.y;
    const int h = kh * 4 + whead;
    const int q0 = qt * 64;
    const int mh = wrow * 32;

    const size_t qbase  = (((size_t)b * NQH + h) * T_SEQ + q0) * HD;
    const size_t kbase  = ((size_t)b * NKVH + kh) * (size_t)T_SEQ * HD;
    const size_t vtbase = ((size_t)b * NKVH + kh) * (size_t)HD * T_SEQ;

    // Q fragments (B operand), 32 rows per wave
    shortx8 qfr[2][2];
    #pragma unroll
    for (int mqt = 0; mqt < 2; mqt++)
        #pragma unroll
        for (int ks = 0; ks < 2; ks++)
            qfr[mqt][ks] = *(const shortx8*)(Qws + qbase +
                (size_t)(mh + mqt * 16 + l16) * HD + ks * 32 + qd * 8);

    const shortx8 ones = {0x3F80, 0x3F80, 0x3F80, 0x3F80,
                          0x3F80, 0x3F80, 0x3F80, 0x3F80};  // bf16 1.0

    floatx4 oaccT[2][4];      // [mqt][dt]: O^T tile, col q = l16, rows d = qd*4+r
    #pragma unroll
    for (int mqt = 0; mqt < 2; mqt++)
        #pragma unroll
        for (int dt = 0; dt < 4; dt++)
            oaccT[mqt][dt] = (floatx4){0.f, 0.f, 0.f, 0.f};
    floatx4 psum[2];          // ones^T P^T: every element = full row-sum for q=l16
    psum[0] = (floatx4){0.f, 0.f, 0.f, 0.f};
    psum[1] = (floatx4){0.f, 0.f, 0.f, 0.f};

    const int lrow = lane >> 3;
    const int cgw  = (lane & 7) ^ lrow;
    const int xr   = l16 & 7;
    const int rb   = wave * 8;     // 8 waves x 8 rows = 64 rows per buffer

    // prologue: stage chunk 0 into buffer 0
    dma16(Kws  + kbase  + (size_t)(rb + lrow) * HD + cgw * 8, &Ks[0][rb * 64]);
    dma16(Vtws + vtbase + (size_t)(rb + lrow) * T_SEQ + cgw * 8, &Vt[0][rb * 64]);

    for (int c = 0; c <= qt; c++) {
        const int cur = c & 1;
        __syncthreads();          // chunk c landed; buffer cur^1 free
        if (c < qt) {
            const int j0n = (c + 1) * 64;
            dma16(Kws  + kbase  + (size_t)(j0n + rb + lrow) * HD + cgw * 8,
                  &Ks[cur ^ 1][rb * 64]);
            dma16(Vtws + vtbase + (size_t)(rb + lrow) * T_SEQ + j0n + cgw * 8,
                  &Vt[cur ^ 1][rb * 64]);
        }

        const bool diag = (c == qt);

        #pragma unroll
        for (int kp = 0; kp < 2; kp++) {
            // diag chunk, row-half 0: keys 32..63 all > q rows 0..31 -> skip
            if (!(diag && wrow == 0 && kp == 1)) {
                // K fragments (A operand) for this 32-key window
                shortx8 kf[2][2];
                #pragma unroll
                for (int ktl = 0; ktl < 2; ktl++) {
                    const int krow = ((kp * 2 + ktl) * 16 + l16) * 64;
                    kf[ktl][0] = *(const shortx8*)&Ks[cur][krow + ((qd ^ xr) * 8)];
                    kf[ktl][1] = *(const shortx8*)&Ks[cur][krow + (((4 | qd) ^ xr) * 8)];
                }

                const bool msk = diag && (wrow == kp);   // diag window straddles row-half

                // ---- S^T = K Q^T, P = 2^S (bf16 RNE via cvt_pk), spill b64 ----
                #pragma unroll
                for (int ktl = 0; ktl < 2; ktl++) {
                    #pragma unroll
                    for (int mqt = 0; mqt < 2; mqt++) {
                        floatx4 s = (floatx4){0.f, 0.f, 0.f, 0.f};
                        s = __builtin_amdgcn_mfma_f32_16x16x32_bf16(kf[ktl][0], qfr[mqt][0], s, 0, 0, 0);
                        s = __builtin_amdgcn_mfma_f32_16x16x32_bf16(kf[ktl][1], qfr[mqt][1], s, 0, 0, 0);
                        float pe[4];
                        #pragma unroll
                        for (int r = 0; r < 4; r++) pe[r] = EXP2F(s[r]);
                        if (msk) {
                            const int qrel  = mh + mqt * 16 + l16;
                            const int jbase = kp * 32 + ktl * 16 + qd * 4;
                            #pragma unroll
                            for (int r = 0; r < 4; r++)
                                if (jbase + r > qrel) pe[r] = 0.f;
                        }
                        uint2 dw;
                        dw.x = cvtpk_bf16(pe[0], pe[1]);
                        dw.y = cvtpk_bf16(pe[2], pe[3]);
                        *(uint2*)&Ps[wave][mqt * 16 + l16][ktl * 16 + qd * 4] = dw;
                    }
                }

                // ---- P^T fragments (B operand; same-wave LDS round trip) ----
                shortx8 pfr[2];
                #pragma unroll
                for (int mqt = 0; mqt < 2; mqt++)
                    pfr[mqt] = *(const shortx8*)&Ps[wave][mqt * 16 + l16][qd * 8];

                // ---- row-sum fused as MFMA: psum += 1 * P^T ----
                #pragma unroll
                for (int mqt = 0; mqt < 2; mqt++)
                    psum[mqt] = __builtin_amdgcn_mfma_f32_16x16x32_bf16(
                        ones, pfr[mqt], psum[mqt], 0, 0, 0);

                // ---- O^T += V^T P^T ----
                __builtin_amdgcn_s_setprio(1);
                #pragma unroll
                for (int dt = 0; dt < 4; dt++) {
                    const shortx8 vf = *(const shortx8*)
                        &Vt[cur][(dt * 16 + l16) * 64 + (((kp * 4 + qd) ^ xr) * 8)];
                    #pragma unroll
                    for (int mqt = 0; mqt < 2; mqt++)
                        oaccT[mqt][dt] = __builtin_amdgcn_mfma_f32_16x16x32_bf16(
                            vf, pfr[mqt], oaccT[mqt][dt], 0, 0, 0);
                }
                __builtin_amdgcn_s_setprio(0);
            }
        }
    }

    // psum rows are identical (A = ones) -> denominator lane-local, no shuffles
    float inv[2];
    inv[0] = 1.f / psum[0][0];
    inv[1] = 1.f / psum[1][0];

    // ---- epilogue: O^T C-layout (col q = l16, rows d = qd*4+r) -> float4 ----
    #pragma unroll
    for (int mqt = 0; mqt < 2; mqt++) {
        const int t = q0 + mh + mqt * 16 + l16;
        float* orow = out + ((size_t)b * T_SEQ + t) * (NQH * HD) + h * HD + qd * 4;
        #pragma unroll
        for (int dt = 0; dt < 4; dt++) {
            float4 o;
            o.x = oaccT[mqt][dt][0] * inv[mqt];
            o.y = oaccT[mqt][dt][1] * inv[mqt];
            o.z = oaccT[mqt][dt][2] * inv[mqt];
            o.w = oaccT[mqt][dt][3] * inv[mqt];
            *(float4*)(orow + dt * 16) = o;
        }
    }
}

extern "C" void kernel_launch(void* const* d_in, const int* in_sizes, int n_in,
                              void* d_out, int out_size, void* d_ws, size_t ws_size,
                              hipStream_t stream) {
    const float* x  = (const float*)d_in[0];
    const float* Wq = (const float*)d_in[1];
    const float* Wk = (const float*)d_in[2];
    const float* Wv = (const float*)d_in[3];
    float* out = (float*)d_out;

    unsigned short* wt  = (unsigned short*)d_ws;                  // 12.6 MB
    unsigned short* Qws = wt  + (size_t)NTOT * DM;                // 16.8 MB
    unsigned short* Kws = Qws + (size_t)2 * NQH * T_SEQ * HD;     // 4.2 MB
    unsigned short* Vws = Kws + (size_t)2 * NKVH * T_SEQ * HD;    // 4.2 MB

    cvt_w   <<<1536, 256, 0, stream>>>(Wq, Wk, Wv, wt);
    qkv_gemm<<<dim3(24, 32), 256, 0, stream>>>(x, wt, Qws, Kws, Vws);
    attn_fwd<<<dim3(32, NKVH, 2), 512, 0, stream>>>(Qws, Kws, Vws, out);
}

// Round 13
// 209.197 us; speedup vs baseline: 3.6729x; 1.3281x over previous
//
#include <hip/hip_runtime.h>

typedef float floatx4 __attribute__((ext_vector_type(4)));
typedef short shortx8 __attribute__((ext_vector_type(8)));

#define T_SEQ 2048
#define NQH   32
#define NKVH  8
#define HD    64
#define DM    2048
#define NTOT  3072

#if __has_builtin(__builtin_amdgcn_exp2f)
#define EXP2F(x) __builtin_amdgcn_exp2f(x)
#else
#define EXP2F(x) exp2f(x)
#endif

__device__ __forceinline__ unsigned short f2bf(float f) {
    unsigned int u = __builtin_bit_cast(unsigned int, f);
    u += 0x7FFFu + ((u >> 16) & 1u);          // RNE
    return (unsigned short)(u >> 16);
}
__device__ __forceinline__ unsigned int pk2bf(float a, float b) {
    return (unsigned int)f2bf(a) | ((unsigned int)f2bf(b) << 16);
}

// v_cvt_pk_bf16_f32: dst = {lo16=bf16(lo), hi16=bf16(hi)}, RNE, 1 instr
__device__ __forceinline__ unsigned int cvtpk_bf16(float lo, float hi) {
    unsigned int r;
    asm("v_cvt_pk_bf16_f32 %0, %1, %2" : "=v"(r) : "v"(lo), "v"(hi));
    return r;
}

// async global->LDS, 16B per lane; LDS dest = wave-uniform base + lane*16
__device__ __forceinline__ void dma16(const unsigned short* g, unsigned short* l) {
    __builtin_amdgcn_global_load_lds(
        (const __attribute__((address_space(1))) unsigned int*)g,
        (__attribute__((address_space(3))) unsigned int*)l,
        16, 0, 0);
}

// ---------------------------------------------------------------------------
// Fused conversion (R5 version — best measured, 205.6us config): blocks
// [0,4096) convert x fp32->bf16 (into d_out scratch); blocks [4096,4096+1536)
// transpose-convert W -> Wt [n][k] bf16 via XOR-granule-swizzled LDS (write
// k-pairs as b32 scatter: 32 banks, 2 lanes/bank = free; read rows as b128).
// ---------------------------------------------------------------------------
__global__ __launch_bounds__(256) void cvt_fused(
    const float* __restrict__ x, const float* __restrict__ Wq,
    const float* __restrict__ Wk, const float* __restrict__ Wv,
    unsigned short* __restrict__ xb, unsigned short* __restrict__ wt)
{
    __shared__ __align__(16) unsigned short Ts[64 * 64];   // logical [n][k], swizzled
    const int id = blockIdx.x;
    const int t = threadIdx.x;
    if (id < 4096) {
        size_t i = ((size_t)id * 256 + t) * 8;
        float4 a = *(const float4*)(x + i);
        float4 b = *(const float4*)(x + i + 4);
        uint4 o;
        o.x = pk2bf(a.x, a.y); o.y = pk2bf(a.z, a.w);
        o.z = pk2bf(b.x, b.y); o.w = pk2bf(b.z, b.w);
        *(uint4*)(xb + i) = o;
        return;
    }
    const int id2 = id - 4096;
    const int k0 = (id2 & 31) * 64, n0g = (id2 >> 5) * 64;
    const float* W; int ldW, col0;
    if (n0g < 2048)      { W = Wq; ldW = 2048; col0 = n0g; }
    else if (n0g < 2560) { W = Wk; ldW = 512;  col0 = n0g - 2048; }
    else                 { W = Wv; ldW = 512;  col0 = n0g - 2560; }
    {
        // thread: k rows {2R, 2R+1}, n cols C..C+7
        const int R = t >> 3, C = (t & 7) * 8;
        const float* src0 = W + (size_t)(k0 + 2 * R) * ldW + col0 + C;
        const float* src1 = src0 + ldW;
        float4 a0 = *(const float4*)(src0);
        float4 a1 = *(const float4*)(src0 + 4);
        float4 b0 = *(const float4*)(src1);
        float4 b1 = *(const float4*)(src1 + 4);
        float lo[8] = {a0.x, a0.y, a0.z, a0.w, a1.x, a1.y, a1.z, a1.w};
        float hi[8] = {b0.x, b0.y, b0.z, b0.w, b1.x, b1.y, b1.z, b1.w};
        const int g = R >> 2;                 // granule of k=2R
        const int ko = (2 * R) & 7;           // short offset within granule (even)
        #pragma unroll
        for (int i = 0; i < 8; i++) {
            const int n = C + i;
            const int gp = g ^ ((n >> 3) & 7);
            *(unsigned int*)&Ts[n * 64 + gp * 8 + ko] = pk2bf(lo[i], hi[i]);
        }
    }
    __syncthreads();
    {
        const int n = t >> 2, kc = (t & 3) * 16;
        const int f = (n >> 3) & 7;
        const int g0 = kc >> 3;
        uint4 o0 = *(const uint4*)&Ts[n * 64 + ((g0)     ^ f) * 8];
        uint4 o1 = *(const uint4*)&Ts[n * 64 + ((g0 + 1) ^ f) * 8];
        unsigned short* d = wt + (size_t)(n0g + n) * DM + k0 + kc;
        *(uint4*)d = o0; *(uint4*)(d + 8) = o1;
    }
}

// ---------------------------------------------------------------------------
// Fused QKV GEMM, all-bf16, SINGLE-buffered LDS (m97 structure: 2 barriers
// per K-step). 32 KiB LDS -> one dispatch round at 768 blocks. Proven ~61us
// (R2/R5). Deep-pipeline variants (R3/R4) and fused-A variants (R11/R12)
// all measured worse -> this is the structural ceiling for this tile shape.
// ---------------------------------------------------------------------------
__global__ __launch_bounds__(256, 4) void qkv_gemm(
    const unsigned short* __restrict__ xb,   // [4096][2048]
    const unsigned short* __restrict__ wt,   // [3072][2048]
    unsigned short* __restrict__ Qws, unsigned short* __restrict__ Kws,
    unsigned short* __restrict__ Vws)
{
    __shared__ __align__(16) unsigned short At[128 * 64];
    __shared__ __align__(16) unsigned short Bt[128 * 64];

    const int tid = threadIdx.x;
    const int wave = tid >> 6, lane = tid & 63;
    const int l16 = lane & 15, qd = lane >> 4;

    const int id  = blockIdx.y * 24 + blockIdx.x;       // 0..767
    const int xcd = id & 7, j = id >> 3;                // j 0..95
    const int m0 = (xcd * 4 + (j & 3)) * 128;           // 32 m-tiles
    const int n0 = (j >> 2) * 128;                      // 24 n-tiles

    const int mh = (wave >> 1) * 64, nh = (wave & 1) * 64;

    const int lrow = lane >> 3;
    const int cgw  = (lane & 7) ^ lrow;            // DMA global col-group swizzle
    const int cg0  = (qd ^ (l16 & 7)) * 8;         // frag col offset, ks=0
    const int cg1  = ((4 | qd) ^ (l16 & 7)) * 8;   // ks=1

    floatx4 acc[4][4];
    #pragma unroll
    for (int mi = 0; mi < 4; mi++)
        #pragma unroll
        for (int ni = 0; ni < 4; ni++)
            acc[mi][ni] = (floatx4){0.f, 0.f, 0.f, 0.f};

    size_t gA[4], gB[4];
    int lofs[4];
    #pragma unroll
    for (int jj = 0; jj < 4; jj++) {
        const int rb = wave * 32 + jj * 8;
        gA[jj] = (size_t)(m0 + rb + lrow) * DM + cgw * 8;
        gB[jj] = (size_t)(n0 + rb + lrow) * DM + cgw * 8;
        lofs[jj] = rb * 64;
    }

    // prologue: stage tile 0
    #pragma unroll
    for (int jj = 0; jj < 4; jj++) {
        dma16(xb + gA[jj], &At[lofs[jj]]);
        dma16(wt + gB[jj], &Bt[lofs[jj]]);
    }

    for (int k0 = 0; k0 < DM; k0 += 64) {
        __syncthreads();          // vmcnt(0) drained before barrier -> tile k0 landed
        #pragma unroll
        for (int ks = 0; ks < 2; ks++) {
            const int cg = ks ? cg1 : cg0;
            shortx8 af[4], bfr[4];
            #pragma unroll
            for (int i = 0; i < 4; i++) {
                af[i]  = *(const shortx8*)&At[(mh + i * 16 + l16) * 64 + cg];
                bfr[i] = *(const shortx8*)&Bt[(nh + i * 16 + l16) * 64 + cg];
            }
            #pragma unroll
            for (int mi = 0; mi < 4; mi++)
                #pragma unroll
                for (int ni = 0; ni < 4; ni++)
                    acc[mi][ni] = __builtin_amdgcn_mfma_f32_16x16x32_bf16(
                        af[mi], bfr[ni], acc[mi][ni], 0, 0, 0);
        }
        __syncthreads();          // all waves done reading LDS
        if (k0 + 64 < DM) {
            #pragma unroll
            for (int jj = 0; jj < 4; jj++) {
                dma16(xb + gA[jj] + k0 + 64, &At[lofs[jj]]);
                dma16(wt + gB[jj] + k0 + 64, &Bt[lofs[jj]]);
            }
        }
    }

    int ncol, H; unsigned short* dst; float sc; bool vtrans;
    if (n0 < 2048)      { ncol = n0;        dst = Qws; H = NQH;  sc = 0.125f * 1.44269504f; vtrans = false; }
    else if (n0 < 2560) { ncol = n0 - 2048; dst = Kws; H = NKVH; sc = 1.0f; vtrans = false; }
    else                { ncol = n0 - 2560; dst = Vws; H = NKVH; sc = 1.0f; vtrans = true;  }

    #pragma unroll
    for (int mi = 0; mi < 4; mi++)
        #pragma unroll
        for (int ni = 0; ni < 4; ni++)
            #pragma unroll
            for (int r = 0; r < 4; r++) {
                int m  = m0 + mh + mi * 16 + qd * 4 + r;
                int nc = ncol + nh + ni * 16 + l16;
                int b  = m >> 11, t = m & (T_SEQ - 1);
                int hh = nc >> 6, d = nc & 63;
                float v = acc[mi][ni][r] * sc;
                size_t idx = vtrans
                    ? ((((size_t)b * H + hh) * HD + d) << 11) + t
                    : ((((size_t)b * H + hh) * T_SEQ + t) << 6) + d;
                dst[idx] = f2bf(v);
            }
}

// ---------------------------------------------------------------------------
// Causal GQA flash attention, transposed form: S^T = K Q^T, O^T = V^T P^T.
// PROVEN R2 body (60.0us measured): serial per-kp chunk body, 2 buffers,
// __syncthreads full-drain per chunk. 8 waves x 512 threads; row-sum fused
// into an all-ones MFMA; P pack via v_cvt_pk_bf16_f32; diag-chunk wave-half
// skip; setprio(1) around PV. Pipelined variants measured worse (R10) or
// corrupt (R7/R8) -> this is the kept structure.
// ---------------------------------------------------------------------------
__global__ __launch_bounds__(512, 4) void attn_fwd(
    const unsigned short* __restrict__ Qws,
    const unsigned short* __restrict__ Kws,
    const unsigned short* __restrict__ Vtws,
    float* __restrict__ out)
{
    __shared__ __align__(16) unsigned short Ks[2][64 * 64];
    __shared__ __align__(16) unsigned short Vt[2][64 * 64];
    __shared__ __align__(16) unsigned short Ps[8][32][40];   // per-wave [q in 32][key in 32-window]

    const int tid = threadIdx.x;
    const int wave = tid >> 6, lane = tid & 63;
    const int whead = wave & 3, wrow = wave >> 2;
    const int l16 = lane & 15, qd = lane >> 4;
    const int b = blockIdx.z;
    const int qt = b ? blockIdx.x : (31 - blockIdx.x);   // CU-pair makespan balance
    const int kh = blockIdx.y;
    const int h = kh * 4 + whead;
    const int q0 = qt * 64;
    const int mh = wrow * 32;

    const size_t qbase  = (((size_t)b * NQH + h) * T_SEQ + q0) * HD;
    const size_t kbase  = ((size_t)b * NKVH + kh) * (size_t)T_SEQ * HD;
    const size_t vtbase = ((size_t)b * NKVH + kh) * (size_t)HD * T_SEQ;

    // Q fragments (B operand), 32 rows per wave
    shortx8 qfr[2][2];
    #pragma unroll
    for (int mqt = 0; mqt < 2; mqt++)
        #pragma unroll
        for (int ks = 0; ks < 2; ks++)
            qfr[mqt][ks] = *(const shortx8*)(Qws + qbase +
                (size_t)(mh + mqt * 16 + l16) * HD + ks * 32 + qd * 8);

    const shortx8 ones = {0x3F80, 0x3F80, 0x3F80, 0x3F80,
                          0x3F80, 0x3F80, 0x3F80, 0x3F80};  // bf16 1.0

    floatx4 oaccT[2][4];      // [mqt][dt]: O^T tile, col q = l16, rows d = qd*4+r
    #pragma unroll
    for (int mqt = 0; mqt < 2; mqt++)
        #pragma unroll
        for (int dt = 0; dt < 4; dt++)
            oaccT[mqt][dt] = (floatx4){0.f, 0.f, 0.f, 0.f};
    floatx4 psum[2];          // ones^T P^T: every element = full row-sum for q=l16
    psum[0] = (floatx4){0.f, 0.f, 0.f, 0.f};
    psum[1] = (floatx4){0.f, 0.f, 0.f, 0.f};

    const int lrow = lane >> 3;
    const int cgw  = (lane & 7) ^ lrow;
    const int xr   = l16 & 7;
    const int rb   = wave * 8;     // 8 waves x 8 rows = 64 rows per buffer

    // prologue: stage chunk 0 into buffer 0
    dma16(Kws  + kbase  + (size_t)(rb + lrow) * HD + cgw * 8, &Ks[0][rb * 64]);
    dma16(Vtws + vtbase + (size_t)(rb + lrow) * T_SEQ + cgw * 8, &Vt[0][rb * 64]);

    for (int c = 0; c <= qt; c++) {
        const int cur = c & 1;
        __syncthreads();          // chunk c landed; buffer cur^1 free
        if (c < qt) {
            const int j0n = (c + 1) * 64;
            dma16(Kws  + kbase  + (size_t)(j0n + rb + lrow) * HD + cgw * 8,
                  &Ks[cur ^ 1][rb * 64]);
            dma16(Vtws + vtbase + (size_t)(rb + lrow) * T_SEQ + j0n + cgw * 8,
                  &Vt[cur ^ 1][rb * 64]);
        }

        const bool diag = (c == qt);

        #pragma unroll
        for (int kp = 0; kp < 2; kp++) {
            // diag chunk, row-half 0: keys 32..63 all > q rows 0..31 -> skip
            if (!(diag && wrow == 0 && kp == 1)) {
                // K fragments (A operand) for this 32-key window
                shortx8 kf[2][2];
                #pragma unroll
                for (int ktl = 0; ktl < 2; ktl++) {
                    const int krow = ((kp * 2 + ktl) * 16 + l16) * 64;
                    kf[ktl][0] = *(const shortx8*)&Ks[cur][krow + ((qd ^ xr) * 8)];
                    kf[ktl][1] = *(const shortx8*)&Ks[cur][krow + (((4 | qd) ^ xr) * 8)];
                }

                const bool msk = diag && (wrow == kp);   // diag window straddles row-half

                // ---- S^T = K Q^T, P = 2^S (bf16 RNE via cvt_pk), spill b64 ----
                #pragma unroll
                for (int ktl = 0; ktl < 2; ktl++) {
                    #pragma unroll
                    for (int mqt = 0; mqt < 2; mqt++) {
                        floatx4 s = (floatx4){0.f, 0.f, 0.f, 0.f};
                        s = __builtin_amdgcn_mfma_f32_16x16x32_bf16(kf[ktl][0], qfr[mqt][0], s, 0, 0, 0);
                        s = __builtin_amdgcn_mfma_f32_16x16x32_bf16(kf[ktl][1], qfr[mqt][1], s, 0, 0, 0);
                        float pe[4];
                        #pragma unroll
                        for (int r = 0; r < 4; r++) pe[r] = EXP2F(s[r]);
                        if (msk) {
                            const int qrel  = mh + mqt * 16 + l16;
                            const int jbase = kp * 32 + ktl * 16 + qd * 4;
                            #pragma unroll
                            for (int r = 0; r < 4; r++)
                                if (jbase + r > qrel) pe[r] = 0.f;
                        }
                        uint2 dw;
                        dw.x = cvtpk_bf16(pe[0], pe[1]);
                        dw.y = cvtpk_bf16(pe[2], pe[3]);
                        *(uint2*)&Ps[wave][mqt * 16 + l16][ktl * 16 + qd * 4] = dw;
                    }
                }

                // ---- P^T fragments (B operand; same-wave LDS round trip) ----
                shortx8 pfr[2];
                #pragma unroll
                for (int mqt = 0; mqt < 2; mqt++)
                    pfr[mqt] = *(const shortx8*)&Ps[wave][mqt * 16 + l16][qd * 8];

                // ---- row-sum fused as MFMA: psum += 1 * P^T ----
                #pragma unroll
                for (int mqt = 0; mqt < 2; mqt++)
                    psum[mqt] = __builtin_amdgcn_mfma_f32_16x16x32_bf16(
                        ones, pfr[mqt], psum[mqt], 0, 0, 0);

                // ---- O^T += V^T P^T ----
                __builtin_amdgcn_s_setprio(1);
                #pragma unroll
                for (int dt = 0; dt < 4; dt++) {
                    const shortx8 vf = *(const shortx8*)
                        &Vt[cur][(dt * 16 + l16) * 64 + (((kp * 4 + qd) ^ xr) * 8)];
                    #pragma unroll
                    for (int mqt = 0; mqt < 2; mqt++)
                        oaccT[mqt][dt] = __builtin_amdgcn_mfma_f32_16x16x32_bf16(
                            vf, pfr[mqt], oaccT[mqt][dt], 0, 0, 0);
                }
                __builtin_amdgcn_s_setprio(0);
            }
        }
    }

    // psum rows are identical (A = ones) -> denominator lane-local, no shuffles
    float inv[2];
    inv[0] = 1.f / psum[0][0];
    inv[1] = 1.f / psum[1][0];

    // ---- epilogue: O^T C-layout (col q = l16, rows d = qd*4+r) -> float4 ----
    #pragma unroll
    for (int mqt = 0; mqt < 2; mqt++) {
        const int t = q0 + mh + mqt * 16 + l16;
        float* orow = out + ((size_t)b * T_SEQ + t) * (NQH * HD) + h * HD + qd * 4;
        #pragma unroll
        for (int dt = 0; dt < 4; dt++) {
            float4 o;
            o.x = oaccT[mqt][dt][0] * inv[mqt];
            o.y = oaccT[mqt][dt][1] * inv[mqt];
            o.z = oaccT[mqt][dt][2] * inv[mqt];
            o.w = oaccT[mqt][dt][3] * inv[mqt];
            *(float4*)(orow + dt * 16) = o;
        }
    }
}

extern "C" void kernel_launch(void* const* d_in, const int* in_sizes, int n_in,
                              void* d_out, int out_size, void* d_ws, size_t ws_size,
                              hipStream_t stream) {
    const float* x  = (const float*)d_in[0];
    const float* Wq = (const float*)d_in[1];
    const float* Wk = (const float*)d_in[2];
    const float* Wv = (const float*)d_in[3];
    float* out = (float*)d_out;

    // xb scratch lives in d_out (16.8 MB of 33.5 MB) — dead before attn writes.
    unsigned short* xb  = (unsigned short*)d_out;
    unsigned short* wt  = (unsigned short*)d_ws;                  // 12.6 MB
    unsigned short* Qws = wt  + (size_t)NTOT * DM;                // 16.8 MB
    unsigned short* Kws = Qws + (size_t)2 * NQH * T_SEQ * HD;     // 4.2 MB
    unsigned short* Vws = Kws + (size_t)2 * NKVH * T_SEQ * HD;    // 4.2 MB

    cvt_fused<<<4096 + 1536, 256, 0, stream>>>(x, Wq, Wk, Wv, xb, wt);
    qkv_gemm <<<dim3(24, 32), 256, 0, stream>>>(xb, wt, Qws, Kws, Vws);
    attn_fwd <<<dim3(32, NKVH, 2), 512, 0, stream>>>(Qws, Kws, Vws, out);
}